// Round 4
// baseline (3555.061 us; speedup 1.0000x reference)
//
#include <hip/hip_runtime.h>
#include <hip/hip_bf16.h>

#define TT 16000
#define BB 4
#define NLAYER 16

typedef unsigned short ushort_t;

__device__ __forceinline__ float bf2f(unsigned short u) {
  unsigned int x = ((unsigned int)u) << 16;
  float f; __builtin_memcpy(&f, &x, 4); return f;
}
__device__ __forceinline__ unsigned short f2bf(float f) {
  unsigned int x; __builtin_memcpy(&x, &f, 4);
  x += 0x7fffu + ((x >> 16) & 1u);   // RNE
  return (unsigned short)(x >> 16);
}

// ---------------------------------------------------------------------------
// Prep: repack f32 weights into k-major layouts; build upsample A-operand
// AT (320x320).
// ---------------------------------------------------------------------------
__global__ __launch_bounds__(256) void kprep(
    const float* __restrict__ feat,
    const float* __restrict__ cond_w, const float* __restrict__ cond_b,
    const float* __restrict__ dil_w, const float* __restrict__ dil_b,
    const float* __restrict__ res_w, const float* __restrict__ skip_w,
    const float* __restrict__ skip_b, const float* __restrict__ out_w,
    const float* __restrict__ end_w,
    float* __restrict__ Wcomb, float* __restrict__ Bcomb,
    float* __restrict__ RWT, float* __restrict__ SWT, float* __restrict__ SBsum,
    float* __restrict__ OWT, float* __restrict__ EWT, float* __restrict__ AT) {
  int tid = blockIdx.x * 256 + threadIdx.x;
  int np = gridDim.x * 256;
  // Wcomb [16][208][128]: rows 0..63 = dil tap0 (x_prev), 64..127 = dil tap1
  // (x_cur), 128..207 = cond_w slice. Column = output channel o (0..127).
  for (int idx = tid; idx < NLAYER * 208 * 128; idx += np) {
    int o = idx & 127, k = (idx >> 7) % 208, i = idx / (208 * 128);
    float v;
    if (k < 64)       v = dil_w[((i * 128 + o) * 64 + k) * 2 + 0];
    else if (k < 128) v = dil_w[((i * 128 + o) * 64 + (k - 64)) * 2 + 1];
    else              v = cond_w[(i * 128 + o) * 80 + (k - 128)];
    Wcomb[idx] = v;
  }
  for (int idx = tid; idx < NLAYER * 128; idx += np)
    Bcomb[idx] = dil_b[idx] + cond_b[idx];
  // RWT [15][64][64] = res_w[i][o][k] -> [i][k][o]
  for (int idx = tid; idx < 15 * 64 * 64; idx += np) {
    int o = idx & 63, k = (idx >> 6) & 63, i = idx >> 12;
    RWT[idx] = res_w[(i * 64 + o) * 64 + k];
  }
  // SWT [16][64][256]: SWT[(i*64+k)*256+o] = skip_w[i][o][k]
  for (int idx = tid; idx < NLAYER * 64 * 256; idx += np) {
    int o = idx & 255; int ki = idx >> 8; int i = ki >> 6, k = ki & 63;
    SWT[idx] = skip_w[(i * 256 + o) * 64 + k];
  }
  for (int idx = tid; idx < 256; idx += np) {
    float s = 0.f;
    for (int i = 0; i < NLAYER; i++) s += skip_b[i * 256 + idx];
    SBsum[idx] = s;
  }
  for (int idx = tid; idx < 256 * 256; idx += np) {
    int o = idx & 255, s = idx >> 8;
    OWT[idx] = out_w[o * 256 + s];   // OWT[s][o]
    EWT[idx] = end_w[o * 256 + s];   // EWT[s][o]
  }
  // AT [K=320][M=320]: km = m*80+i, mrow = b*80+q, value feat[b,i,q-m]
  for (int idx = tid; idx < 320 * 320; idx += np) {
    int mrow = idx % 320, km = idx / 320;
    int b = mrow / 80, q = mrow % 80;
    int m = km / 80, i = km % 80;
    int j = q - m;
    AT[idx] = (j >= 0) ? feat[(b * 80 + i) * 80 + j] : 0.f;
  }
}

// ---------------------------------------------------------------------------
// x0[b][r][t] = embed[forward_input[b][t]][r]  (stored bf16)
// ---------------------------------------------------------------------------
__global__ __launch_bounds__(256) void kembed(const int* __restrict__ fin,
    const float* __restrict__ embed, ushort_t* __restrict__ x0) {
  int b = blockIdx.y;
  int t = blockIdx.x * 256 + threadIdx.x;
  if (t >= TT) return;
  int id = fin[b * TT + t];
  const float* e = embed + id * 64;
  ushort_t* xo = x0 + (size_t)b * 64 * TT + t;
  #pragma unroll 8
  for (int k = 0; k < 64; k++) xo[k * TT] = f2bf(e[k]);
}

// ---------------------------------------------------------------------------
// Upsample GEMM: cond[b,o,200q+r] = sum_{i,m} feat[b,i,q-m]*up_w[i,o,200m+r].
// (320 M)x(320 K)x(16000 N). up_w chunk staged in LDS (gathered directly),
// AT rows via wave-uniform loads. cond stored f32.
// ---------------------------------------------------------------------------
__global__ __launch_bounds__(256) void kup(const float* __restrict__ AT,
    const float* __restrict__ up_w, const float* __restrict__ up_b,
    float* __restrict__ cond) {
  __shared__ float wbuf[64][64];
  int t0 = blockIdx.x * 64;
  int m0 = blockIdx.y * 64;
  int lane = threadIdx.x & 63;
  int w = __builtin_amdgcn_readfirstlane(threadIdx.x >> 6);
  int mw = m0 + w * 16;
  float acc[16];
  #pragma unroll
  for (int j = 0; j < 16; j++) acc[j] = 0.f;
  for (int kc = 0; kc < 5; kc++) {
    for (int f = threadIdx.x; f < 4096; f += 256) {
      int k = f >> 6, j = f & 63;
      int km = kc * 64 + k;       // km = m*80+i
      int m = km / 80, i = km % 80;
      int col = t0 + j;           // col = o*200+r
      int o = col / 200, r = col % 200;
      wbuf[k][j] = up_w[(size_t)(i * 80 + o) * 800 + m * 200 + r];
    }
    __syncthreads();
    for (int k = 0; k < 64; k++) {
      float v = wbuf[k][lane];
      const float* arow = AT + (kc * 64 + k) * 320 + mw;
      #pragma unroll
      for (int j = 0; j < 16; j++) acc[j] += arow[j] * v;
    }
    __syncthreads();
  }
  int col = t0 + lane;
  int o = col / 200, r = col % 200;
  float bias = up_b[o];
  #pragma unroll
  for (int j = 0; j < 16; j++) {
    int mrow = mw + j;
    int b = mrow / 80, q = mrow % 80;
    cond[(size_t)(b * 80 + o) * TT + q * 200 + r] = acc[j] + bias;
  }
}

// ---------------------------------------------------------------------------
// One WaveNet layer. Block = one b, 64 t-columns. Gate waves own 16
// channel-pairs each (p0=w*16); skip waves own 64 outputs each (o0=w*64).
// skipacc[B,256,T] f32 is written (layer 0, init with SBsum) or RMW-added
// (layers 1..15). Layer 15: res/x-update is dead code -> skipped.
// ---------------------------------------------------------------------------
__global__ __launch_bounds__(256) void klayer(
    const ushort_t* __restrict__ xin, ushort_t* __restrict__ xout,
    const float* __restrict__ cond,
    const float* __restrict__ WB, const float* __restrict__ Bb,
    const float* __restrict__ RW, const float* __restrict__ rb,
    const float* __restrict__ SW, float* __restrict__ skipacc,
    const float* __restrict__ SBsum,
    int d, int first, int last) {
  __shared__ float xc[64][64];
  __shared__ float xp[64][64];
  __shared__ float av[64][64];
  int b = blockIdx.y;
  int t0 = blockIdx.x * 64;
  int lane = threadIdx.x & 63;
  int w = __builtin_amdgcn_readfirstlane(threadIdx.x >> 6);
  int p0 = w * 16;
  const ushort_t* xinb = xin + (size_t)b * 64 * TT;
  for (int f = threadIdx.x; f < 4096; f += 256) {
    int k = f >> 6, t = f & 63;
    xc[k][t] = bf2f(xinb[k * TT + t0 + t]);
    int tp = t0 + t - d;
    xp[k][t] = (tp >= 0) ? bf2f(xinb[k * TT + tp]) : 0.f;
  }
  __syncthreads();
  float aa[16], ab[16];
  #pragma unroll
  for (int j = 0; j < 16; j++) { aa[j] = Bb[p0 + j]; ab[j] = Bb[64 + p0 + j]; }
  // dilated conv taps (k-major combined weight rows)
  for (int k = 0; k < 64; k++) {
    float vp = xp[k][lane], vc = xc[k][lane];
    const float* W0 = WB + k * 128;
    const float* W1 = WB + (64 + k) * 128;
    #pragma unroll
    for (int j = 0; j < 16; j++) {
      aa[j] += W0[p0 + j] * vp + W1[p0 + j] * vc;
      ab[j] += W0[64 + p0 + j] * vp + W1[64 + p0 + j] * vc;
    }
  }
  // conditioning matmul (cond f32, L2/L3 resident)
  const float* cb = cond + (size_t)b * 80 * TT + t0 + lane;
  for (int c = 0; c < 80; c++) {
    float v = cb[c * TT];
    const float* W2 = WB + (128 + c) * 128;
    #pragma unroll
    for (int j = 0; j < 16; j++) {
      aa[j] += W2[p0 + j] * v;
      ab[j] += W2[64 + p0 + j] * v;
    }
  }
  #pragma unroll
  for (int j = 0; j < 16; j++) {
    float ax = fabsf(aa[j]);
    float e2 = __expf(-2.f * ax);                       // <= 1, no overflow
    float th = __builtin_copysignf((1.f - e2) / (1.f + e2), aa[j]);
    float sg = 1.f / (1.f + __expf(-ab[j]));
    av[p0 + j][lane] = th * sg;
  }
  __syncthreads();
  // skip matmul: each wave computes 64 of the 256 skip outputs
  {
    int o0 = w * 64;
    float sacc[64];
    #pragma unroll
    for (int j = 0; j < 64; j++) sacc[j] = 0.f;
    for (int k = 0; k < 64; k++) {
      float v = av[k][lane];
      const float* S = SW + k * 256 + o0;
      #pragma unroll
      for (int j = 0; j < 64; j++) sacc[j] += S[j] * v;
    }
    float* sp = skipacc + ((size_t)b * 256 + o0) * TT + t0 + lane;
    if (first) {
      #pragma unroll
      for (int j = 0; j < 64; j++) sp[(size_t)j * TT] = SBsum[o0 + j] + sacc[j];
    } else {
      #pragma unroll
      for (int j = 0; j < 64; j++) sp[(size_t)j * TT] += sacc[j];
    }
  }
  if (!last) {
    float ar[16];
    #pragma unroll
    for (int j = 0; j < 16; j++) ar[j] = rb[p0 + j];
    for (int k = 0; k < 64; k++) {
      float v = av[k][lane];
      const float* R = RW + k * 64;
      #pragma unroll
      for (int j = 0; j < 16; j++) ar[j] += R[p0 + j] * v;
    }
    ushort_t* xo = xout + (size_t)b * 64 * TT + t0 + lane;
    #pragma unroll
    for (int j = 0; j < 16; j++)
      xo[(size_t)(p0 + j) * TT] = f2bf(ar[j] + xc[p0 + j][lane]);
  }
}

// ---------------------------------------------------------------------------
// Final: relu(skipacc) -> out_w (256x256) -> relu -> end_w (256x256) ->
// shift-by-1 -> f32 store (d_out is float: reference output dtype is f32!).
// ---------------------------------------------------------------------------
__global__ __launch_bounds__(256) void kfinal(
    const float* __restrict__ skipacc, const float* __restrict__ OWT,
    const float* __restrict__ EWT, float* __restrict__ dout) {
  __shared__ ushort_t pool[256][64];
  __shared__ ushort_t mdb[256][64];
  int b = blockIdx.y;
  int t0 = blockIdx.x * 64;
  int lane = threadIdx.x & 63;
  int w = __builtin_amdgcn_readfirstlane(threadIdx.x >> 6);
  int o0 = w * 64;
  for (int f = threadIdx.x; f < 16384; f += 256) {
    int o = f >> 6, tl = f & 63;
    float v = skipacc[((size_t)b * 256 + o) * TT + t0 + tl];
    pool[o][tl] = f2bf(fmaxf(v, 0.f));
  }
  __syncthreads();
  float acc[64];
  #pragma unroll
  for (int j = 0; j < 64; j++) acc[j] = 0.f;
  for (int k = 0; k < 256; k++) {
    float v = bf2f(pool[k][lane]);
    const float* O = OWT + k * 256 + o0;
    #pragma unroll
    for (int j = 0; j < 64; j++) acc[j] += O[j] * v;
  }
  #pragma unroll
  for (int j = 0; j < 64; j++) mdb[o0 + j][lane] = f2bf(fmaxf(acc[j], 0.f));
  __syncthreads();
  #pragma unroll
  for (int j = 0; j < 64; j++) acc[j] = 0.f;
  for (int k = 0; k < 256; k++) {
    float v = bf2f(mdb[k][lane]);
    const float* E = EWT + k * 256 + o0;
    #pragma unroll
    for (int j = 0; j < 64; j++) acc[j] += E[j] * v;
  }
  int gt = t0 + lane;
  float* ob = dout + (size_t)b * 256 * TT;
  #pragma unroll
  for (int j = 0; j < 64; j++) {
    int o = o0 + j;
    if (gt == 0) ob[(size_t)o * TT] = 0.f;
    if (gt + 1 < TT) ob[(size_t)o * TT + gt + 1] = acc[j];
  }
}

// ---------------------------------------------------------------------------
extern "C" void kernel_launch(void* const* d_in, const int* in_sizes, int n_in,
                              void* d_out, int out_size, void* d_ws, size_t ws_size,
                              hipStream_t stream) {
  const float* feat   = (const float*)d_in[0];
  const int*   fin    = (const int*)d_in[1];
  const float* embed  = (const float*)d_in[2];
  const float* up_w   = (const float*)d_in[3];
  const float* up_b   = (const float*)d_in[4];
  const float* cond_w = (const float*)d_in[5];
  const float* cond_b = (const float*)d_in[6];
  const float* dil_w  = (const float*)d_in[7];
  const float* dil_b  = (const float*)d_in[8];
  const float* res_w  = (const float*)d_in[9];
  const float* res_b  = (const float*)d_in[10];
  const float* skip_w = (const float*)d_in[11];
  const float* skip_b = (const float*)d_in[12];
  const float* out_w  = (const float*)d_in[13];
  const float* end_w  = (const float*)d_in[14];

  // Workspace layout (~99 MB): f32 region first, then bf16 region.
  float* ws = (float*)d_ws;
  size_t off = 0;
  float* skipacc = ws + off; off += (size_t)BB * 256 * TT;  // 16,384,000
  float* cond  = ws + off; off += (size_t)BB * 80 * TT;     //  5,120,000
  float* Wcomb = ws + off; off += (size_t)NLAYER * 208 * 128;
  float* Bcomb = ws + off; off += NLAYER * 128;
  float* RWT   = ws + off; off += 15 * 64 * 64;
  float* SWT   = ws + off; off += (size_t)NLAYER * 64 * 256;
  float* SBsum = ws + off; off += 256;
  float* OWT   = ws + off; off += 256 * 256;
  float* EWT   = ws + off; off += 256 * 256;
  float* AT    = ws + off; off += 320 * 320;
  ushort_t* ub = (ushort_t*)(ws + off);
  size_t uoff = 0;
  ushort_t* x0 = ub + uoff; uoff += (size_t)BB * 64 * TT;   // bf16
  ushort_t* x1 = ub + uoff; uoff += (size_t)BB * 64 * TT;   // bf16

  kprep<<<512, 256, 0, stream>>>(feat, cond_w, cond_b, dil_w, dil_b,
      res_w, skip_w, skip_b, out_w, end_w,
      Wcomb, Bcomb, RWT, SWT, SBsum, OWT, EWT, AT);
  kembed<<<dim3((TT + 255) / 256, BB), 256, 0, stream>>>(fin, embed, x0);
  kup<<<dim3(250, 5), 256, 0, stream>>>(AT, up_w, up_b, cond);
  for (int i = 0; i < NLAYER; i++) {
    int d = 1 << (i % 8);
    const ushort_t* xin = (i & 1) ? x1 : x0;
    ushort_t* xout = (i & 1) ? x0 : x1;
    int last = (i == NLAYER - 1) ? 1 : 0;
    klayer<<<dim3(250, BB), 256, 0, stream>>>(xin, xout, cond,
        Wcomb + (size_t)i * 208 * 128, Bcomb + i * 128,
        RWT + (size_t)(last ? 0 : i) * 64 * 64, res_b + (last ? 0 : i) * 64,
        SWT + (size_t)i * 64 * 256, skipacc, SBsum,
        d, (i == 0) ? 1 : 0, last);
  }
  kfinal<<<dim3(250, BB), 256, 0, stream>>>(skipacc, OWT, EWT,
      (float*)d_out);
}

// Round 5
// 530.079 us; speedup vs baseline: 6.7067x; 6.7067x over previous
//
#include <hip/hip_runtime.h>
#include <hip/hip_bf16.h>

#define TT 16000
#define BB 4
#define NLAYER 16
#define USTR 232    // klayer stage-1 B-operand row stride (shorts): 224 + 8 pad
#define U2STR 72    // acts row stride (shorts): 64 + 8 pad
#define M3STR 264   // kfinal mid row stride (shorts): 256 + 8 pad

#define A1SZ (NLAYER*8*7*512)   // gate-weight A-frags
#define A2SZ (NLAYER*4*2*512)   // res-weight A-frags
#define SWSZ (16*32*512)        // skip-weight A-frags (M=256, K=1024)
#define OWSZ (16*8*512)         // out/end-weight A-frags (M=256, K=256)

typedef unsigned short ushort_t;
typedef short v8s __attribute__((ext_vector_type(8)));
typedef short v4s __attribute__((ext_vector_type(4)));
typedef float v4f __attribute__((ext_vector_type(4)));

#define MFMA16 __builtin_amdgcn_mfma_f32_16x16x32_bf16

__device__ __forceinline__ float bf2f(ushort_t u) {
  unsigned int x = ((unsigned int)u) << 16;
  float f; __builtin_memcpy(&f, &x, 4); return f;
}
__device__ __forceinline__ ushort_t f2bf(float f) {
  unsigned int x; __builtin_memcpy(&x, &f, 4);
  x += 0x7fffu + ((x >> 16) & 1u);   // RNE
  return (ushort_t)(x >> 16);
}

// ---------------------------------------------------------------------------
// Prep: pack every weight matrix into exact MFMA A-fragment order (bf16), so
// kernels load fragments with one coalesced dwordx4 per lane.
// A-frag layout: elem j of lane l for tile = A[m = mt*16 + (l&15)]
//                                           [k = ks*32 + (l>>4)*8 + j]
// ---------------------------------------------------------------------------
__global__ __launch_bounds__(256) void kprep(
    const float* __restrict__ feat,
    const float* __restrict__ cond_w, const float* __restrict__ cond_b,
    const float* __restrict__ dil_w, const float* __restrict__ dil_b,
    const float* __restrict__ res_w, const float* __restrict__ skip_w,
    const float* __restrict__ skip_b, const float* __restrict__ out_w,
    const float* __restrict__ end_w,
    ushort_t* __restrict__ A1, ushort_t* __restrict__ A2,
    ushort_t* __restrict__ SWf, ushort_t* __restrict__ OWf,
    ushort_t* __restrict__ EWf,
    float* __restrict__ Bcomb, float* __restrict__ SBsum,
    float* __restrict__ AT) {
  int tid = blockIdx.x * 256 + threadIdx.x;
  int np = gridDim.x * 256;
  // A1: gate GEMM [16 layers][8 Mtiles][7 Ksteps][64 lanes][8]
  // K rows: 0..63 = xc (tap1), 64..127 = xp (tap0), 128..207 = cond, pad=0
  for (int idx = tid; idx < A1SZ; idx += np) {
    int j = idx & 7, lane = (idx >> 3) & 63;
    int r_ = idx >> 9;
    int ks = r_ % 7; int r2 = r_ / 7;
    int mt = r2 & 7; int i = r2 >> 3;
    int m = mt * 16 + (lane & 15);
    int k = ks * 32 + (lane >> 4) * 8 + j;
    float v = 0.f;
    if (k < 64)       v = dil_w[((i * 128 + m) * 64 + k) * 2 + 1];
    else if (k < 128) v = dil_w[((i * 128 + m) * 64 + (k - 64)) * 2 + 0];
    else if (k < 208) v = cond_w[(i * 128 + m) * 80 + (k - 128)];
    A1[idx] = f2bf(v);
  }
  // A2: res GEMM [16][4 Mtiles][2 Ksteps][64][8] (layer 15 zeroed/unused)
  for (int idx = tid; idx < A2SZ; idx += np) {
    int j = idx & 7, lane = (idx >> 3) & 63;
    int r_ = idx >> 9;
    int ks = r_ & 1; int mt = (r_ >> 1) & 3; int i = r_ >> 3;
    int m = mt * 16 + (lane & 15);
    int k = ks * 32 + (lane >> 4) * 8 + j;
    A2[idx] = f2bf(i < 15 ? res_w[(i * 64 + m) * 64 + k] : 0.f);
  }
  // SWf: skip GEMM [16 Mtiles][32 Ksteps][64][8], K = layer*64 + ch
  for (int idx = tid; idx < SWSZ; idx += np) {
    int j = idx & 7, lane = (idx >> 3) & 63;
    int r_ = idx >> 9;
    int ks = r_ & 31; int mt = r_ >> 5;
    int m = mt * 16 + (lane & 15);
    int k = ks * 32 + (lane >> 4) * 8 + j;
    int i = k >> 6, ch = k & 63;
    SWf[idx] = f2bf(skip_w[(i * 256 + m) * 64 + ch]);
  }
  // OWf/EWf: [16 Mtiles][8 Ksteps][64][8]
  for (int idx = tid; idx < OWSZ; idx += np) {
    int j = idx & 7, lane = (idx >> 3) & 63;
    int r_ = idx >> 9;
    int ks = r_ & 7; int mt = r_ >> 3;
    int m = mt * 16 + (lane & 15);
    int k = ks * 32 + (lane >> 4) * 8 + j;
    OWf[idx] = f2bf(out_w[m * 256 + k]);
    EWf[idx] = f2bf(end_w[m * 256 + k]);
  }
  for (int idx = tid; idx < NLAYER * 128; idx += np)
    Bcomb[idx] = dil_b[idx] + cond_b[idx];
  for (int idx = tid; idx < 256; idx += np) {
    float s = 0.f;
    for (int i = 0; i < NLAYER; i++) s += skip_b[i * 256 + idx];
    SBsum[idx] = s;
  }
  // AT [K=320][M=320]: km = m*80+i, mrow = b*80+q, value feat[b,i,q-m]
  for (int idx = tid; idx < 320 * 320; idx += np) {
    int mrow = idx % 320, km = idx / 320;
    int b = mrow / 80, q = mrow % 80;
    int m = km / 80, i = km % 80;
    int j = q - m;
    AT[idx] = (j >= 0) ? feat[(b * 80 + i) * 80 + j] : 0.f;
  }
}

// ---------------------------------------------------------------------------
// x0[b][t][r] = embed[forward_input[b][t]][r]  (bf16, t-major rows)
// ---------------------------------------------------------------------------
__global__ __launch_bounds__(256) void kembed(const int* __restrict__ fin,
    const float* __restrict__ embed, ushort_t* __restrict__ x0) {
  int b = blockIdx.y;
  int t = blockIdx.x * 256 + threadIdx.x;
  if (t >= TT) return;
  int id = fin[b * TT + t];
  const float* e = embed + id * 64;
  ushort_t* xo = x0 + ((size_t)b * TT + t) * 64;
  #pragma unroll 8
  for (int k = 0; k < 64; k++) xo[k] = f2bf(e[k]);
}

// ---------------------------------------------------------------------------
// Upsample GEMM (fp32 VALU — only ~3.3 GFLOP, already <20 µs in R4).
// Output layout now cond[b][t][80] bf16 (t-major for klayer staging).
// ---------------------------------------------------------------------------
__global__ __launch_bounds__(256) void kup(const float* __restrict__ AT,
    const float* __restrict__ up_w, const float* __restrict__ up_b,
    ushort_t* __restrict__ cond) {
  __shared__ float wbuf[64][64];
  int t0 = blockIdx.x * 64;
  int m0 = blockIdx.y * 64;
  int lane = threadIdx.x & 63;
  int w = __builtin_amdgcn_readfirstlane(threadIdx.x >> 6);
  int mw = m0 + w * 16;
  float acc[16];
  #pragma unroll
  for (int j = 0; j < 16; j++) acc[j] = 0.f;
  for (int kc = 0; kc < 5; kc++) {
    for (int f = threadIdx.x; f < 4096; f += 256) {
      int k = f >> 6, j = f & 63;
      int km = kc * 64 + k;       // km = m*80+i
      int m = km / 80, i = km % 80;
      int col = t0 + j;           // col = o*200+r
      int o = col / 200, r = col % 200;
      wbuf[k][j] = up_w[(size_t)(i * 80 + o) * 800 + m * 200 + r];
    }
    __syncthreads();
    for (int k = 0; k < 64; k++) {
      float v = wbuf[k][lane];
      const float* arow = AT + (kc * 64 + k) * 320 + mw;
      #pragma unroll
      for (int j = 0; j < 16; j++) acc[j] += arow[j] * v;
    }
    __syncthreads();
  }
  int col = t0 + lane;
  int o = col / 200, r = col % 200;
  float bias = up_b[o];
  #pragma unroll
  for (int j = 0; j < 16; j++) {
    int mrow = mw + j;
    int b = mrow / 80, q = mrow % 80;
    cond[((size_t)b * TT + q * 200 + r) * 80 + o] = f2bf(acc[j] + bias);
  }
}

// ---------------------------------------------------------------------------
// One WaveNet layer, MFMA. Block = (64 t) x (one b). 4 waves.
// Stage 1: gate GEMM M=128, K=224 (xc|xp|cond|pad), N=64. Wave w owns
// M-tiles {w, w+4} so channel p and p+64 land in the same lane/reg ->
// lane-local tanh*sigmoid. Acts -> LDS U2 (B-layout) + global (bf16,
// deferred skip). Stage 2: res GEMM M=64 K=64 + residual -> x ping-pong.
// ---------------------------------------------------------------------------
__global__ __launch_bounds__(256) void klayer(
    const ushort_t* __restrict__ xin, ushort_t* __restrict__ xout,
    const ushort_t* __restrict__ cond, ushort_t* __restrict__ actsl,
    const ushort_t* __restrict__ A1l, const ushort_t* __restrict__ A2l,
    const float* __restrict__ Bb, const float* __restrict__ rbias,
    int d, int last) {
  __shared__ ushort_t U[64 * USTR];    // 29.0 KB: B-operand [t][k]
  __shared__ ushort_t U2[64 * U2STR];  //  9.0 KB: acts [t][ch]
  int b = blockIdx.y;
  int t0 = blockIdx.x * 64;
  int tidx = threadIdx.x;
  int lane = tidx & 63;
  int w = tidx >> 6;
  int tl = lane & 15, quad = lane >> 4;

  // ---- stage B-operand: U[t][0..63]=xc, [64..127]=xp, [128..207]=cond ----
  const ushort_t* xb = xin + ((size_t)b * TT + t0) * 64;
  for (int e = tidx * 8; e < 4096; e += 2048) {
    int t = e >> 6, c = e & 63;
    *(v8s*)&U[t * USTR + c] = *(const v8s*)(xb + e);
  }
  for (int e = tidx * 8; e < 4096; e += 2048) {
    int t = e >> 6, c = e & 63;
    int tp = t0 + t - d;
    v8s v = 0;
    if (tp >= 0) v = *(const v8s*)(xin + ((size_t)b * TT + tp) * 64 + c);
    *(v8s*)&U[t * USTR + 64 + c] = v;
  }
  const ushort_t* cbp = cond + ((size_t)b * TT + t0) * 80;
  for (int e = tidx * 8; e < 5120; e += 2048) {
    int t = e / 80, c = e - t * 80;
    *(v8s*)&U[t * USTR + 128 + c] = *(const v8s*)(cbp + e);
  }
  {  // zero K-pad 208..223 (must be finite: mfma multiplies it)
    int e = tidx * 4;
    int t = e >> 4, c = e & 15;
    *(v4s*)&U[t * USTR + 208 + c] = (v4s)0;
  }
  __syncthreads();

  // ---- stage 1: gate GEMM ----
  v4f acc0[4], acc1[4];
  #pragma unroll
  for (int nt = 0; nt < 4; nt++) { acc0[nt] = 0.f; acc1[nt] = 0.f; }
  #pragma unroll
  for (int ks = 0; ks < 7; ks++) {
    v8s a0 = *(const v8s*)(A1l + (((size_t)w * 7 + ks) * 64 + lane) * 8);
    v8s a1 = *(const v8s*)(A1l + (((size_t)(w + 4) * 7 + ks) * 64 + lane) * 8);
    #pragma unroll
    for (int nt = 0; nt < 4; nt++) {
      v8s bf = *(const v8s*)&U[(nt * 16 + tl) * USTR + ks * 32 + quad * 8];
      acc0[nt] = MFMA16(a0, bf, acc0[nt], 0, 0, 0);
      acc1[nt] = MFMA16(a1, bf, acc1[nt], 0, 0, 0);
    }
  }

  // ---- gates: ch = w*16 + quad*4 + r (pair ch, ch+64 lane-local) ----
  int cha = w * 16 + quad * 4;
  float ba[4], bb_[4];
  #pragma unroll
  for (int r = 0; r < 4; r++) { ba[r] = Bb[cha + r]; bb_[r] = Bb[64 + cha + r]; }
  #pragma unroll
  for (int nt = 0; nt < 4; nt++) {
    int t = nt * 16 + tl;
    #pragma unroll
    for (int r = 0; r < 4; r++) {
      float ia = acc0[nt][r] + ba[r];
      float ib = acc1[nt][r] + bb_[r];
      float ax = fabsf(ia);
      float e2 = __expf(-2.f * ax);
      float th = __builtin_copysignf((1.f - e2) / (1.f + e2), ia);
      float sg = 1.f / (1.f + __expf(-ib));
      U2[t * U2STR + cha + r] = f2bf(th * sg);
    }
  }
  __syncthreads();

  // ---- acts -> global (vectorized, deferred skip GEMM reads these) ----
  ushort_t* ab = actsl + ((size_t)b * TT + t0) * 64;
  for (int e = tidx * 8; e < 4096; e += 2048) {
    int t = e >> 6, c = e & 63;
    *(v8s*)(ab + e) = *(const v8s*)&U2[t * U2STR + c];
  }

  // ---- stage 2: res GEMM + residual (dead code at layer 15) ----
  if (!last) {
    v4f acc2[4];
    #pragma unroll
    for (int nt = 0; nt < 4; nt++) {
      v4f z;
      #pragma unroll
      for (int r = 0; r < 4; r++) z[r] = rbias[cha + r];
      acc2[nt] = z;
    }
    #pragma unroll
    for (int ks = 0; ks < 2; ks++) {
      v8s a = *(const v8s*)(A2l + (((size_t)w * 2 + ks) * 64 + lane) * 8);
      #pragma unroll
      for (int nt = 0; nt < 4; nt++) {
        v8s bf = *(const v8s*)&U2[(nt * 16 + tl) * U2STR + ks * 32 + quad * 8];
        acc2[nt] = MFMA16(a, bf, acc2[nt], 0, 0, 0);
      }
    }
    // residual add (xc from U k<64), park in U xp-region for vector store
    #pragma unroll
    for (int nt = 0; nt < 4; nt++) {
      int t = nt * 16 + tl;
      #pragma unroll
      for (int r = 0; r < 4; r++) {
        float xcv = bf2f(U[t * USTR + cha + r]);
        U[t * USTR + 64 + cha + r] = f2bf(acc2[nt][r] + xcv);
      }
    }
    __syncthreads();
    ushort_t* xob = xout + ((size_t)b * TT + t0) * 64;
    for (int e = tidx * 8; e < 4096; e += 2048) {
      int t = e >> 6, c = e & 63;
      *(v8s*)(xob + e) = *(const v8s*)&U[t * USTR + 64 + c];
    }
  }
}

// ---------------------------------------------------------------------------
// Final fused MFMA chain: skip GEMM (M=256, K=1024, acts b-frags gathered
// straight from global) +SBsum -> relu -> out (K=256 via LDS) -> relu ->
// end -> shift-by-1 -> f32 store. Wave w owns M-tiles w*4..w*4+3.
// ---------------------------------------------------------------------------
__global__ __launch_bounds__(256) void kfinal(
    const ushort_t* __restrict__ actsb,
    const ushort_t* __restrict__ SWf, const ushort_t* __restrict__ OWf,
    const ushort_t* __restrict__ EWf, const float* __restrict__ SBsum,
    float* __restrict__ dout) {
  __shared__ ushort_t M3[64 * M3STR];  // 33 KB mid buffer [t][ch]
  int b = blockIdx.y;
  int t0 = blockIdx.x * 64;
  int lane = threadIdx.x & 63;
  int w = threadIdx.x >> 6;
  int tl = lane & 15, quad = lane >> 4;

  // ---- skip GEMM, K = 16 layers * 64 ch ----
  v4f acc[4][4];
  #pragma unroll
  for (int mt = 0; mt < 4; mt++) {
    int o = (w * 4 + mt) * 16 + quad * 4;
    #pragma unroll
    for (int nt = 0; nt < 4; nt++) {
      v4f z;
      #pragma unroll
      for (int r = 0; r < 4; r++) z[r] = SBsum[o + r];
      acc[mt][nt] = z;
    }
  }
  for (int l = 0; l < NLAYER; l++) {
    const ushort_t* al = actsb + (((size_t)l * BB + b) * TT + t0) * 64;
    #pragma unroll
    for (int ks2 = 0; ks2 < 2; ks2++) {
      int ksg = l * 2 + ks2;
      v8s bf[4];
      #pragma unroll
      for (int nt = 0; nt < 4; nt++)
        bf[nt] = *(const v8s*)(al + (nt * 16 + tl) * 64 + ks2 * 32 + quad * 8);
      #pragma unroll
      for (int mt = 0; mt < 4; mt++) {
        v8s a = *(const v8s*)(SWf + (((size_t)(w * 4 + mt) * 32 + ksg) * 64 + lane) * 8);
        #pragma unroll
        for (int nt = 0; nt < 4; nt++)
          acc[mt][nt] = MFMA16(a, bf[nt], acc[mt][nt], 0, 0, 0);
      }
    }
  }
  #pragma unroll
  for (int mt = 0; mt < 4; mt++) {
    int o = (w * 4 + mt) * 16 + quad * 4;
    #pragma unroll
    for (int nt = 0; nt < 4; nt++) {
      int t = nt * 16 + tl;
      #pragma unroll
      for (int r = 0; r < 4; r++)
        M3[t * M3STR + o + r] = f2bf(fmaxf(acc[mt][nt][r], 0.f));
    }
  }
  __syncthreads();

  // ---- out GEMM, K=256 ----
  v4f acc2[4][4];
  #pragma unroll
  for (int mt = 0; mt < 4; mt++)
    #pragma unroll
    for (int nt = 0; nt < 4; nt++) acc2[mt][nt] = 0.f;
  #pragma unroll
  for (int ks = 0; ks < 8; ks++) {
    v8s bf[4];
    #pragma unroll
    for (int nt = 0; nt < 4; nt++)
      bf[nt] = *(const v8s*)&M3[(nt * 16 + tl) * M3STR + ks * 32 + quad * 8];
    #pragma unroll
    for (int mt = 0; mt < 4; mt++) {
      v8s a = *(const v8s*)(OWf + (((size_t)(w * 4 + mt) * 8 + ks) * 64 + lane) * 8);
      #pragma unroll
      for (int nt = 0; nt < 4; nt++)
        acc2[mt][nt] = MFMA16(a, bf[nt], acc2[mt][nt], 0, 0, 0);
    }
  }
  __syncthreads();   // all M3 reads done before overwrite
  #pragma unroll
  for (int mt = 0; mt < 4; mt++) {
    int o = (w * 4 + mt) * 16 + quad * 4;
    #pragma unroll
    for (int nt = 0; nt < 4; nt++) {
      int t = nt * 16 + tl;
      #pragma unroll
      for (int r = 0; r < 4; r++)
        M3[t * M3STR + o + r] = f2bf(fmaxf(acc2[mt][nt][r], 0.f));
    }
  }
  __syncthreads();

  // ---- end GEMM, K=256, then shifted store ----
  v4f acc3[4][4];
  #pragma unroll
  for (int mt = 0; mt < 4; mt++)
    #pragma unroll
    for (int nt = 0; nt < 4; nt++) acc3[mt][nt] = 0.f;
  #pragma unroll
  for (int ks = 0; ks < 8; ks++) {
    v8s bf[4];
    #pragma unroll
    for (int nt = 0; nt < 4; nt++)
      bf[nt] = *(const v8s*)&M3[(nt * 16 + tl) * M3STR + ks * 32 + quad * 8];
    #pragma unroll
    for (int mt = 0; mt < 4; mt++) {
      v8s a = *(const v8s*)(EWf + (((size_t)(w * 4 + mt) * 8 + ks) * 64 + lane) * 8);
      #pragma unroll
      for (int nt = 0; nt < 4; nt++)
        acc3[mt][nt] = MFMA16(a, bf[nt], acc3[mt][nt], 0, 0, 0);
    }
  }
  #pragma unroll
  for (int mt = 0; mt < 4; mt++) {
    #pragma unroll
    for (int nt = 0; nt < 4; nt++) {
      int tg = t0 + nt * 16 + tl;
      #pragma unroll
      for (int r = 0; r < 4; r++) {
        int o = (w * 4 + mt) * 16 + quad * 4 + r;
        float* ob = dout + ((size_t)b * 256 + o) * TT;
        if (tg == 0) ob[0] = 0.f;
        if (tg + 1 < TT) ob[tg + 1] = acc3[mt][nt][r];
      }
    }
  }
}

// ---------------------------------------------------------------------------
extern "C" void kernel_launch(void* const* d_in, const int* in_sizes, int n_in,
                              void* d_out, int out_size, void* d_ws, size_t ws_size,
                              hipStream_t stream) {
  const float* feat   = (const float*)d_in[0];
  const int*   fin    = (const int*)d_in[1];
  const float* embed  = (const float*)d_in[2];
  const float* up_w   = (const float*)d_in[3];
  const float* up_b   = (const float*)d_in[4];
  const float* cond_w = (const float*)d_in[5];
  const float* cond_b = (const float*)d_in[6];
  const float* dil_w  = (const float*)d_in[7];
  const float* dil_b  = (const float*)d_in[8];
  const float* res_w  = (const float*)d_in[9];
  const float* res_b  = (const float*)d_in[10];
  const float* skip_w = (const float*)d_in[11];
  const float* skip_b = (const float*)d_in[12];
  const float* out_w  = (const float*)d_in[13];
  const float* end_w  = (const float*)d_in[14];

  // Workspace (~160 MB; R1 ran with 209 MB so ws_size is sufficient).
  float* ws = (float*)d_ws;
  size_t off = 0;
  float* AT    = ws + off; off += 320 * 320;
  float* Bcomb = ws + off; off += NLAYER * 128;
  float* SBsum = ws + off; off += 256;
  ushort_t* ub = (ushort_t*)(ws + off);
  size_t uo = 0;
  ushort_t* A1   = ub + uo; uo += A1SZ;
  ushort_t* A2   = ub + uo; uo += A2SZ;
  ushort_t* SWf  = ub + uo; uo += SWSZ;
  ushort_t* OWf  = ub + uo; uo += OWSZ;
  ushort_t* EWf  = ub + uo; uo += OWSZ;
  ushort_t* cond = ub + uo; uo += (size_t)BB * TT * 80;
  ushort_t* x0   = ub + uo; uo += (size_t)BB * TT * 64;
  ushort_t* x1   = ub + uo; uo += (size_t)BB * TT * 64;
  ushort_t* acts = ub + uo; uo += (size_t)NLAYER * BB * TT * 64;  // 131 MB

  kprep<<<512, 256, 0, stream>>>(feat, cond_w, cond_b, dil_w, dil_b,
      res_w, skip_w, skip_b, out_w, end_w,
      A1, A2, SWf, OWf, EWf, Bcomb, SBsum, AT);
  kembed<<<dim3((TT + 255) / 256, BB), 256, 0, stream>>>(fin, embed, x0);
  kup<<<dim3(250, 5), 256, 0, stream>>>(AT, up_w, up_b, cond);
  for (int i = 0; i < NLAYER; i++) {
    int d = 1 << (i % 8);
    const ushort_t* xin = (i & 1) ? x1 : x0;
    ushort_t* xout = (i & 1) ? x0 : x1;
    int last = (i == NLAYER - 1) ? 1 : 0;
    klayer<<<dim3(250, BB), 256, 0, stream>>>(xin, xout, cond,
        acts + (size_t)i * BB * TT * 64,
        A1 + (size_t)i * 8 * 7 * 512, A2 + (size_t)i * 4 * 2 * 512,
        Bcomb + i * 128, res_b + (last ? 0 : i) * 64, d, last);
  }
  kfinal<<<dim3(250, BB), 256, 0, stream>>>(acts, SWf, OWf, EWf, SBsum,
      (float*)d_out);
}